// Round 6
// baseline (715.485 us; speedup 1.0000x reference)
//
#include <hip/hip_runtime.h>
#include <math.h>

// Problem constants (fixed by the reference)
#define BB 128
#define NN 2048
#define HH 300
#define EE 20
#define MM 200
#define NEGV (-10000.0f)
#define SCORES_OFF (BB * (NN + 1))   // new_mem starts here in d_out

// B-image geometry (LDS-ready layout, built by k_prep2, streamed by k_main)
#define NCOL 208                     // 200 cols padded to 13*16
#define KSTEPS 10                    // K: 300 padded to 320 = 10*32
#define ROWSH 72                     // shorts per col: hi[32] | lo[32] | pad[8] = 144 B
#define KIMG (NCOL * ROWSH)          // shorts per (b,kstep) image = 14976 (29952 B)
#define CH16 (KIMG / 8)              // 1872 16-byte chunks per image
#define BIMG_SHORTS ((size_t)BB * KSTEPS * KIMG)

typedef short bf16x8 __attribute__((ext_vector_type(8)));
typedef float f32x4 __attribute__((ext_vector_type(4)));

// ---------------------------------------------------------------------------
// bucket: x<=4 -> x ; else floor(log(x)/log2)+3, clipped to [0,9]
// ---------------------------------------------------------------------------
__device__ __forceinline__ int bucketf(int x) {
  if (x <= 4) return x < 0 ? 0 : x;
  float l = floorf(logf((float)x) / 0.69314718055994530942f);
  int bi = (int)l + 3;
  return bi > 9 ? 9 : bi;
}

// float -> bf16 (RNE) and back, bit ops
__device__ __forceinline__ short f2bf(float f) {
  union { float f; unsigned u; } v; v.f = f;
  unsigned r = (v.u + 0x7FFFu + ((v.u >> 16) & 1u)) >> 16;
  return (short)r;
}
__device__ __forceinline__ float bf2f(short s) {
  union { unsigned u; float f; } v; v.u = ((unsigned)(unsigned short)s) << 16;
  return v.f;
}

// async global->LDS, 16B per lane (global_load_lds_dwordx4)
__device__ __forceinline__ void gload16(const void* g, void* l) {
  __builtin_amdgcn_global_load_lds(
      (const __attribute__((address_space(1))) void*)g,
      (__attribute__((address_space(3))) void*)l, 16, 0, 0);
}

// ---------------------------------------------------------------------------
// k_prep2: ONE dispatch for all prep (unchanged from R5 PASS). Block ranges:
//   [0,13): tables ; [13,93): bias ; [93,221): avg ; [221,1053): Bimg build.
// ---------------------------------------------------------------------------
__global__ void k_prep2(const float* __restrict__ W1, const float* __restrict__ b1,
                        const float* __restrict__ q, const float* __restrict__ mem,
                        const float* __restrict__ dtab, const float* __restrict__ ctab,
                        const float* __restrict__ atab, const int* __restrict__ lact,
                        const int* __restrict__ entc, const int* __restrict__ cell,
                        float* __restrict__ distW, float* __restrict__ cntW,
                        float* __restrict__ bias, float* __restrict__ avg,
                        short* __restrict__ Bimg, float* __restrict__ out) {
  const int blk = blockIdx.x;
  const int tid = threadIdx.x;
  if (blk < 13) {                       // ---- tables: 2*10*200 = 4000 items
    int idx = blk * 320 + tid;
    if (idx >= 2 * 10 * MM) return;
    int t = idx / (10 * MM);
    int r = idx % (10 * MM);
    int d = r / MM;
    int m = r % MM;
    const float* tab = (t == 0) ? dtab : ctab;
    int wrow0 = (t == 0) ? (3 * HH) : (3 * HH + EE);
    float s = 0.f;
#pragma unroll
    for (int e = 0; e < EE; e++) s += tab[d * EE + e] * W1[(wrow0 + e) * MM + m];
    ((t == 0) ? distW : cntW)[d * MM + m] = s;
  } else if (blk < 93) {                // ---- bias: 128*200 = 25600 items
    int idx = (blk - 13) * 320 + tid;
    if (idx >= BB * MM) return;
    int b = idx / MM;
    int m = idx % MM;
    float s = b1[m];
    for (int h = 0; h < HH; h++) s += q[b * HH + h] * W1[(HH + h) * MM + m];
    int la = lact[b];
#pragma unroll
    for (int e = 0; e < EE; e++)
      s += atab[la * EE + e] * W1[(3 * HH + 2 * EE + e) * MM + m];
    bias[idx] = s;
  } else if (blk < 221) {               // ---- avg: 128 batches
    int b = blk - 93;
    int ci = cell[b];
    if (tid < HH) {
      float c = (float)entc[b * NN + ci];
      float m = mem[((size_t)b * NN + ci) * HH + tid];
      avg[b * HH + tid] = (m * c + q[b * HH + tid]) / (c + 1.f);
    } else if (tid == HH) {
      out[b * (NN + 1) + NN] = 0.f;
    }
  } else {                              // ---- Bimg: 266240 items, exact fit
    int idx = (blk - 221) * 320 + tid;  // (b*10+ks)*208+col
    int col = idx % NCOL;
    int bks = idx / NCOL;
    int ks = bks % KSTEPS;
    int b = bks / KSTEPS;
    int k0 = ks * 32;
    const float* qb = q + b * HH;
    short* dst = Bimg + (size_t)idx * ROWSH;
#pragma unroll
    for (int g = 0; g < 4; g++) {
      bf16x8 h8, l8;
#pragma unroll
      for (int i = 0; i < 8; i++) {
        int k = k0 + 8 * g + i;
        float val = 0.f;
        if (k < HH && col < MM) {
          val = fmaf(qb[k], W1[(size_t)(2 * HH + k) * MM + col],
                     W1[(size_t)k * MM + col]);
        }
        short h = f2bf(val);
        h8[i] = h;
        l8[i] = f2bf(val - bf2f(h));
      }
      *(bf16x8*)(dst + g * 8) = h8;          // direct 16B stores from regs
      *(bf16x8*)(dst + 32 + g * 8) = l8;
    }
    *(bf16x8*)(dst + 64) = (bf16x8){0, 0, 0, 0, 0, 0, 0, 0};
  }
}

// ---------------------------------------------------------------------------
// A-side split: issue (loads only) / store new_mem / cvt to bf16 hi/lo.
// ---------------------------------------------------------------------------
__device__ __forceinline__ void issueA(const float* rowp, int kb, float* va) {
  if (kb + 7 < HH) {
    float4 x0 = *(const float4*)(rowp + kb);
    float4 x1 = *(const float4*)(rowp + kb + 4);
    va[0] = x0.x; va[1] = x0.y; va[2] = x0.z; va[3] = x0.w;
    va[4] = x1.x; va[5] = x1.y; va[6] = x1.z; va[7] = x1.w;
  } else {
#pragma unroll
    for (int i = 0; i < 8; i++) {
      int k = kb + i;
      va[i] = (k < HH) ? rowp[k] : 0.f;
    }
  }
}

__device__ __forceinline__ void storeA(const float* va, int kb, float* orow,
                                       const float* avgp, bool subst) {
  if (kb + 7 < HH) {
    float4 o0, o1;
    if (subst) {
      o0 = *(const float4*)(avgp + kb);
      o1 = *(const float4*)(avgp + kb + 4);
    } else {
      o0 = make_float4(va[0], va[1], va[2], va[3]);
      o1 = make_float4(va[4], va[5], va[6], va[7]);
    }
    *(float4*)(orow + kb) = o0;
    *(float4*)(orow + kb + 4) = o1;
  } else {
#pragma unroll
    for (int i = 0; i < 8; i++) {
      int k = kb + i;
      if (k < HH) orow[k] = subst ? avgp[k] : va[i];
    }
  }
}

__device__ __forceinline__ void cvtA(const float* va, bf16x8* ahi, bf16x8* alo) {
#pragma unroll
  for (int i = 0; i < 8; i++) {
    short h = f2bf(va[i]);
    (*ahi)[i] = h;
    (*alo)[i] = f2bf(va[i] - bf2f(h));
  }
}

// ---------------------------------------------------------------------------
// Epilogue: + bias + distW/cntW rows, relu, dot W2, 16-lane reduce.
// C/D layout (m89): col = lane&15 -> m = f*16+lr ; row = 4g+reg -> n.
// ---------------------------------------------------------------------------
__device__ __forceinline__ void epilogue(
    const f32x4* acc, int b, int n0, int w, int lr, int g,
    const float* __restrict__ bias, const float* __restrict__ distW,
    const float* __restrict__ cntW, const float* __restrict__ W2,
    const float* __restrict__ b2, const float* __restrict__ ment,
    const int* __restrict__ entc, const int* __restrict__ dist,
    float* __restrict__ out) {
  const float addc = b2[0] + ment[b];
  const float* bi = bias + b * MM;
  float s[4];
#pragma unroll
  for (int r = 0; r < 4; r++) {
    int nr = n0 + w * 16 + 4 * g + r;
    int db = bucketf(dist[b * NN + nr]);
    int cb = bucketf(entc[b * NN + nr]);
    const float* dW = distW + db * MM;
    const float* cW = cntW + cb * MM;
    float acc_s = 0.f;
#pragma unroll
    for (int f = 0; f < 13; f++) {
      if (f < 12 || lr < 8) {  // m = f*16+lr < 200
        int m = f * 16 + lr;
        float h = acc[f][r] + bi[m] + dW[m] + cW[m];
        acc_s += fmaxf(h, 0.f) * W2[m];
      }
    }
    s[r] = acc_s;
  }
#pragma unroll
  for (int off = 1; off < 16; off <<= 1) {
#pragma unroll
    for (int r = 0; r < 4; r++) s[r] += __shfl_xor(s[r], off);
  }
  if (lr == 0) {
#pragma unroll
    for (int r = 0; r < 4; r++) {
      int nr = n0 + w * 16 + 4 * g + r;
      int mk = entc[b * NN + nr] > 0;
      out[b * (NN + 1) + nr] = mk ? (s[r] + addc) : NEGV;
    }
  }
}

// B-prefetch: 4 wave-slices of gload16 into btS[buf]
#define B_GLOADS(bufptr, bs)                                        \
  {                                                                 \
    _Pragma("unroll") for (int it = 0; it < 4; it++) {              \
      int i = tid + it * 512;                                       \
      if (i < CH16) gload16((bs) + (size_t)i * 8, (bufptr) + i * 8);\
    }                                                               \
  }

// MFMA phase on btS[buf] with current ahi/alo
#define MFMA_PHASE(bufptr)                                                         \
  {                                                                                \
    _Pragma("unroll") for (int f = 0; f < 13; f++) {                               \
      const short* bp = (bufptr) + (f * 16 + lr) * ROWSH + g * 8;                  \
      bf16x8 bhi = *(const bf16x8*)bp;                                             \
      bf16x8 blo = *(const bf16x8*)(bp + 32);                                      \
      acc[f] = __builtin_amdgcn_mfma_f32_16x16x32_bf16(ahi, bhi, acc[f], 0, 0, 0); \
      acc[f] = __builtin_amdgcn_mfma_f32_16x16x32_bf16(alo, bhi, acc[f], 0, 0, 0); \
      acc[f] = __builtin_amdgcn_mfma_f32_16x16x32_bf16(ahi, blo, acc[f], 0, 0, 0); \
    }                                                                              \
  }

// ---------------------------------------------------------------------------
// k_main v4: 2048 blocks x 512 thr (8 waves, 128 rows/block), XCD-pinned.
//   T3/T4 (m201 pattern): raw s_barrier + COUNTED vmcnt — prefetches stay in
//   flight across barriers (the R5 __syncthreads drained vmcnt(0) each kstep,
//   capping in-flight HBM bytes at ~3.3KB/CU vs the ~9KB needed -> 35% BW).
//   Pipeline per kstep ks (per wave, vmem issue order):
//     [4 B-gloads(ks+1) -> btS[ks+1 &1]] [2 A-loads(ks+2) -> va[(ks+2)%3]]
//     [2 stores(ks)] MFMA(btS[ks&1]) vmcnt(4) cvtA(ks+1) s_barrier
//   vmcnt(4) audit: newest-4 = {A(ks+2) x2, st(ks) x2} => B(ks+1) gloads and
//   A(ks+1) loads (older) complete before the barrier. ks=8 issues no A ->
//   vmcnt(2). Full unroll => va[] statically indexed (rule #20).
// ---------------------------------------------------------------------------
__global__ __launch_bounds__(512, 4) void k_main(
    const float* __restrict__ mem, const short* __restrict__ Bimg,
    const float* __restrict__ bias, const float* __restrict__ distW,
    const float* __restrict__ cntW, const float* __restrict__ W2,
    const float* __restrict__ b2, const float* __restrict__ ment,
    const int* __restrict__ entc, const int* __restrict__ dist,
    const int* __restrict__ cell, const float* __restrict__ avg,
    float* __restrict__ out) {
  __shared__ __align__(16) short btS[2][KIMG];  // 59904 B -> 2 blocks/CU

  const int tid = threadIdx.x;
  const int bid = blockIdx.x;
  const int b = (bid & 7) * 16 + (bid >> 7);    // XCD-pinned batch (bijective)
  const int n0 = ((bid >> 3) & 15) * 128;

  const int w = tid >> 6;   // 8 waves: rows [n0+16w, n0+16w+16)
  const int l = tid & 63;
  const int lr = l & 15;
  const int g = l >> 4;

  const int ci = cell[b];
  const int n = n0 + w * 16 + lr;
  const float* rowp = mem + ((size_t)b * NN + n) * HH;
  float* orow = out + SCORES_OFF + ((size_t)b * NN + n) * HH;
  const float* avgp = avg + b * HH;
  const bool subst = (n == ci);
  const short* bsrc = Bimg + (size_t)b * KSTEPS * KIMG;

  f32x4 acc[13];
#pragma unroll
  for (int f = 0; f < 13; f++) acc[f] = (f32x4){0.f, 0.f, 0.f, 0.f};

  float va[3][8];
  bf16x8 ahi, alo;

  // ---- prologue: A(0), B(0), A(1); wait A(0)+B(0); cvt A(0); barrier ----
  issueA(rowp, 0 * 32 + 8 * g, va[0]);
  B_GLOADS(&btS[0][0], bsrc);
  issueA(rowp, 1 * 32 + 8 * g, va[1]);
  asm volatile("s_waitcnt vmcnt(2)" ::: "memory");  // A(0),B(0) done; A(1) may fly
  __builtin_amdgcn_sched_barrier(0);
  cvtA(va[0], &ahi, &alo);
  __builtin_amdgcn_sched_barrier(0);
  __builtin_amdgcn_s_barrier();
  __builtin_amdgcn_sched_barrier(0);

  // ---- steady state: ks = 0..7 (fully unrolled -> static va slots) ----
#pragma unroll
  for (int ks = 0; ks < 8; ks++) {
    B_GLOADS(&btS[(ks + 1) & 1][0], bsrc + (size_t)(ks + 1) * KIMG);
    issueA(rowp, (ks + 2) * 32 + 8 * g, va[(ks + 2) % 3]);
    storeA(va[ks % 3], ks * 32 + 8 * g, orow, avgp, subst);
    MFMA_PHASE(&btS[ks & 1][0]);
    asm volatile("s_waitcnt vmcnt(4)" ::: "memory");
    __builtin_amdgcn_sched_barrier(0);
    cvtA(va[(ks + 1) % 3], &ahi, &alo);
    __builtin_amdgcn_sched_barrier(0);
    __builtin_amdgcn_s_barrier();
    __builtin_amdgcn_sched_barrier(0);
  }

  // ---- ks = 8: no A-issue (A(10) doesn't exist) -> vmcnt(2) ----
  B_GLOADS(&btS[1][0], bsrc + (size_t)9 * KIMG);
  storeA(va[8 % 3], 8 * 32 + 8 * g, orow, avgp, subst);
  MFMA_PHASE(&btS[0][0]);
  asm volatile("s_waitcnt vmcnt(2)" ::: "memory");  // newest-2 = st(8); B(9),A(9) done
  __builtin_amdgcn_sched_barrier(0);
  cvtA(va[9 % 3], &ahi, &alo);
  __builtin_amdgcn_sched_barrier(0);
  __builtin_amdgcn_s_barrier();
  __builtin_amdgcn_sched_barrier(0);

  // ---- ks = 9: last kstep, no barrier needed after ----
  storeA(va[9 % 3], 9 * 32 + 8 * g, orow, avgp, subst);
  MFMA_PHASE(&btS[1][0]);

  epilogue(acc, b, n0, w, lr, g, bias, distW, cntW, W2, b2, ment, entc, dist, out);
}

// ---------------------------------------------------------------------------
extern "C" void kernel_launch(void* const* d_in, const int* in_sizes, int n_in,
                              void* d_out, int out_size, void* d_ws, size_t ws_size,
                              hipStream_t stream) {
  const float* q    = (const float*)d_in[0];
  const float* ment = (const float*)d_in[1];
  const float* mem  = (const float*)d_in[2];
  const int* entc   = (const int*)d_in[3];
  const int* dist   = (const int*)d_in[4];
  const int* lact   = (const int*)d_in[5];
  const int* cell   = (const int*)d_in[6];
  const float* W1   = (const float*)d_in[7];
  const float* b1   = (const float*)d_in[8];
  const float* W2   = (const float*)d_in[9];
  const float* b2   = (const float*)d_in[10];
  const float* dtab = (const float*)d_in[11];
  const float* ctab = (const float*)d_in[12];
  const float* atab = (const float*)d_in[13];
  float* out = (float*)d_out;

  // workspace: Bimg (38.3 MB shorts) | bias | distW | cntW | avg
  short* Bimg  = (short*)d_ws;
  float* fws   = (float*)(Bimg + BIMG_SHORTS);
  float* bias  = fws;
  float* distW = bias + BB * MM;
  float* cntW  = distW + 10 * MM;
  float* avg   = cntW + 10 * MM;

  k_prep2<<<1053, 320, 0, stream>>>(W1, b1, q, mem, dtab, ctab, atab, lact,
                                    entc, cell, distW, cntW, bias, avg, Bimg, out);
  k_main<<<2048, 512, 0, stream>>>(mem, Bimg, bias, distW, cntW, W2, b2, ment,
                                   entc, dist, cell, avg, out);
}